// Round 4
// baseline (636.494 us; speedup 1.0000x reference)
//
#include <hip/hip_runtime.h>
#include <float.h>

// EdgeConv: B=4, N=4096, Fin=64, Fout=64, K=20
// out[b,n,o] = u[b,n,o] + max_{m in knn20(n)} v[b,m,o]
//   u = x.(W1-W2)^T + bias ; v = x.W2^T
// knn on d = sq[n] + sq[m] - 2 x_n.x_m (>=0), self excluded.
//
// R10: K2+K3 fused -> keys NEVER touch HBM. R9 evidence: K2 duration
// invariant to grid size at 3.5 TB/s (write-path/L2 wall), K3 re-reads
// the same 92 MB; the 160+92 MB keys round-trip was ~98 us of 149.
// Fused kernel: 512-thread block = 32 n-rows x ALL 4096 m; per lane the
// wave's key slice lives in 128 VGPRs (256 x 16-bit, statically indexed).
// Then: per-row min (shfl + LDS atomicMin), 128-bin LDS histogram of
// (key-rowmin)>>1 (level-2 >>4 rescan fallback), R8 threshold scan,
// register->LDS candidate collect (cap 64), R8 exact-fp32 re-rank +
// rank-select + v-gather + output. Selection is a superset of R8's
// (hc >= R8 minimal threshold + 1 margin); exact re-rank unchanged.

constexpr int Bb = 4, Nn = 4096, Ff = 64, Kk = 20;

typedef __attribute__((ext_vector_type(8))) short bf16x8;
typedef __attribute__((ext_vector_type(16))) float f32x16;

__device__ inline unsigned int bf16rn(float f) {
  unsigned int u = __float_as_uint(f);
  return (u + 0x7fffu + ((u >> 16) & 1u)) >> 16;
}

// ---------------- K1: u, v, sq, xhi, xlo (swizzled) ----------------
constexpr int RT1 = 16;  // rows per block

__global__ __launch_bounds__(256) void uv_kernel2(
    const float* __restrict__ x, const float* __restrict__ W,
    const float* __restrict__ bvec, float* __restrict__ u,
    float* __restrict__ v, float* __restrict__ sq,
    unsigned short* __restrict__ xhi, unsigned short* __restrict__ xlo) {
  __shared__ __align__(16) float4 Ws[64 * 33];   // W row o at granules [33o,33o+32)
  __shared__ __align__(16) float4 xs[RT1 * 16];  // x row r at [16r..)
  const int t = threadIdx.x, l = t & 63, w = t >> 6;
  const int bn0 = blockIdx.x * RT1;
  #pragma unroll
  for (int i = 0; i < 8; i++) {
    int f = t + 256 * i;  // f4 index into W (64 rows x 32 f4)
    Ws[(f >> 5) * 33 + (f & 31)] = ((const float4*)W)[f];
  }
  xs[t] = ((const float4*)x)[bn0 * 16 + t];
  __syncthreads();
  // bf16 hi/lo split -> MFMA-fragment-swizzled layout
  #pragma unroll
  for (int i = 0; i < 4; i++) {
    int idx = t + 256 * i;   // 0..1023 within block's 16 rows
    int nloc = idx >> 6;     // row within block
    int k = idx & 63;        // channel
    float val = ((const float*)xs)[idx];
    unsigned int hb = bf16rn(val);
    float fhi = __uint_as_float(hb << 16);
    unsigned int lb = bf16rn(val - fhi);
    int ng = bn0 + nloc;  // global flat row (batch-local swizzle folds in)
    size_t flat = ((size_t)(ng >> 5) << 11) + ((size_t)(k >> 4) << 9) +
                  ((size_t)((k >> 3) & 1) << 8) + ((size_t)(ng & 31) << 3) +
                  (size_t)(k & 7);
    xhi[flat] = (unsigned short)hb;
    xlo[flat] = (unsigned short)lb;
  }
  // sq for rows 4w..4w+3
  #pragma unroll
  for (int i = 0; i < 4; i++) {
    int r = 4 * w + i;
    float val = ((const float*)&xs[r * 16])[l];
    float s = val * val;
    #pragma unroll
    for (int d = 32; d; d >>= 1) s += __shfl_xor(s, d, 64);
    if (l == 0) sq[bn0 + r] = s;
  }
  const int o = l;
  float ua[4] = {0.f, 0.f, 0.f, 0.f}, va[4] = {0.f, 0.f, 0.f, 0.f};
  #pragma unroll
  for (int c = 0; c < 16; c++) {
    float4 w1 = Ws[o * 33 + c];
    float4 w2 = Ws[o * 33 + 16 + c];
    float4 wd;
    wd.x = w1.x - w2.x; wd.y = w1.y - w2.y;
    wd.z = w1.z - w2.z; wd.w = w1.w - w2.w;
    #pragma unroll
    for (int i = 0; i < 4; i++) {
      float4 xv = xs[(4 * w + i) * 16 + c];
      ua[i] += xv.x * wd.x + xv.y * wd.y + xv.z * wd.z + xv.w * wd.w;
      va[i] += xv.x * w2.x + xv.y * w2.y + xv.z * w2.z + xv.w * w2.w;
    }
  }
  float bo = bvec[o];
  #pragma unroll
  for (int i = 0; i < 4; i++) {
    size_t row = (size_t)(bn0 + 4 * w + i);
    u[row * 64 + o] = ua[i] + bo;
    v[row * 64 + o] = va[i];
  }
}

// ---------------- fused K2+K3: keys in registers, no HBM keys ----------
// Grid 512 (= Bb * 128 n-tiles). Block 512 threads = 8 waves.
// Wave w: m in [512w, 512(w+1)) over 16 j-tiles of 32.
// C/D: col=lane&31, row=(reg&3)+8*(reg>>2)+4*(lane>>5) [m74/m101].

__global__ __launch_bounds__(512) void fused_knn_kernel(
    const float* __restrict__ x, const unsigned short* __restrict__ xhi,
    const unsigned short* __restrict__ xlo, const float* __restrict__ sq,
    const float* __restrict__ u, const float* __restrict__ v,
    float* __restrict__ out) {
  __shared__ unsigned int rowminS[32];
  __shared__ unsigned int histS[32][128];
  __shared__ int candS[32][64];
  __shared__ unsigned int cntS[32];
  __shared__ unsigned int hcS[32];
  __shared__ int fbS;
  __shared__ unsigned long long keyS[8][64];

  const int t = threadIdx.x, l = t & 63, w = t >> 6;
  const int blk = blockIdx.x;       // 0..511
  const int b = blk >> 7;           // batch
  const int n_base = (blk & 127) * 32;
  const int col = l & 31, half = l >> 5;
  const int m0w = w * 512;

  // init LDS (visible after the pass-1 barrier chain below)
  if (t < 32) { rowminS[t] = 0xFFFFFFFFu; cntS[t] = 0u; }
  if (t == 0) fbS = 0;
  #pragma unroll
  for (int i = 0; i < 8; i++) ((unsigned int*)histS)[t * 8 + i] = 0u;

  const unsigned short* xhb = xhi + (size_t)b * Nn * Ff;
  const unsigned short* xlb = xlo + (size_t)b * Nn * Ff;
  const float* sqb = sq + b * Nn;

  // A fragments (32 rows x 64 ch, hi/lo)
  bf16x8 Ahi[4], Alo[4];
  #pragma unroll
  for (int ks = 0; ks < 4; ks++) {
    size_t off = ((size_t)((n_base >> 5) * 4 + ks) << 9) + ((size_t)l << 3);
    Ahi[ks] = *(const bf16x8*)(xhb + off);
    Alo[ks] = *(const bf16x8*)(xlb + off);
  }
  int rowE[16];
  float sqn_r[16];
  #pragma unroll
  for (int e = 0; e < 16; e++) {
    rowE[e] = (e & 3) + 8 * (e >> 2) + 4 * half;
    sqn_r[e] = sqb[n_base + rowE[e]];
  }
  __syncthreads();  // LDS init complete before any atomics

  // ---- pass 1: MFMA sweep; 256 16-bit keys/lane into 128 VGPRs ----
  unsigned int kpk[16][8];  // [j][e>>1]: lo=e even, hi=e odd (STATIC idx)
  unsigned int kmin[16];
  #pragma unroll
  for (int e = 0; e < 16; e++) kmin[e] = 0xFFFFFFFFu;

  #pragma unroll
  for (int j = 0; j < 16; ++j) {
    const int m0 = m0w + 32 * j;
    const int mblk = m0 >> 5;
    bf16x8 Bhi[4], Blo[4];
    #pragma unroll
    for (int ks = 0; ks < 4; ks++) {
      size_t off = ((size_t)(mblk * 4 + ks) << 9) + ((size_t)l << 3);
      Bhi[ks] = *(const bf16x8*)(xhb + off);
      Blo[ks] = *(const bf16x8*)(xlb + off);
    }
    f32x16 acc = {0.f, 0.f, 0.f, 0.f, 0.f, 0.f, 0.f, 0.f,
                  0.f, 0.f, 0.f, 0.f, 0.f, 0.f, 0.f, 0.f};
    #pragma unroll
    for (int ks = 0; ks < 4; ks++) {
      acc = __builtin_amdgcn_mfma_f32_32x32x16_bf16(Ahi[ks], Bhi[ks], acc, 0, 0, 0);
      acc = __builtin_amdgcn_mfma_f32_32x32x16_bf16(Ahi[ks], Blo[ks], acc, 0, 0, 0);
      acc = __builtin_amdgcn_mfma_f32_32x32x16_bf16(Alo[ks], Bhi[ks], acc, 0, 0, 0);
    }
    const int m = m0 + col;
    const float sm = sqb[m];
    #pragma unroll
    for (int h = 0; h < 8; h++) {
      float d0 = fmaxf(sqn_r[2 * h] + sm - 2.0f * acc[2 * h], 0.f);
      float d1 = fmaxf(sqn_r[2 * h + 1] + sm - 2.0f * acc[2 * h + 1], 0.f);
      unsigned int k0 = __float_as_uint(d0) >> 15;  // fits 16 bits (sign=0)
      unsigned int k1 = __float_as_uint(d1) >> 15;
      if (m == n_base + rowE[2 * h]) k0 = 0xFFFFu;      // self exclusion
      if (m == n_base + rowE[2 * h + 1]) k1 = 0xFFFFu;
      kmin[2 * h] = min(kmin[2 * h], k0);
      kmin[2 * h + 1] = min(kmin[2 * h + 1], k1);
      kpk[j][h] = k0 | (k1 << 16);
    }
  }

  // per-row min: reduce over the 32 col-lanes of each half, then atomicMin
  #pragma unroll
  for (int e = 0; e < 16; e++) {
    unsigned int km = kmin[e];
    #pragma unroll
    for (int d2 = 1; d2 < 32; d2 <<= 1)
      km = min(km, (unsigned int)__shfl_xor((int)km, d2, 64));
    if ((l & 31) == 0) atomicMin(&rowminS[rowE[e]], km);
  }
  __syncthreads();

  // ---- pass 2: histogram bins (key-rowmin)>>1, window 256 quanta ----
  unsigned int rmin[16];
  #pragma unroll
  for (int e = 0; e < 16; e++) rmin[e] = rowminS[rowE[e]];
  #pragma unroll
  for (int j = 0; j < 16; ++j) {
    #pragma unroll
    for (int h = 0; h < 8; h++) {
      unsigned int pk = kpk[j][h];
      unsigned int r0 = (pk & 0xFFFFu) - rmin[2 * h];
      unsigned int r1 = (pk >> 16) - rmin[2 * h + 1];
      if (r0 < 256u) atomicAdd(&histS[rowE[2 * h]][r0 >> 1], 1u);
      if (r1 < 256u) atomicAdd(&histS[rowE[2 * h + 1]][r1 >> 1], 1u);
    }
  }
  __syncthreads();

  // ---- pass 3: per-row threshold (wave w owns rows 4w..4w+3) ----
  #pragma unroll
  for (int i = 0; i < 4; ++i) {
    int r = 4 * w + i;
    unsigned int h0 = histS[r][2 * l], h1 = histS[r][2 * l + 1];
    unsigned int ls = h0 + h1, cum = ls;
    #pragma unroll
    for (int d2 = 1; d2 < 64; d2 <<= 1) {
      unsigned int o = (unsigned int)__shfl_up((int)cum, d2, 64);
      cum += (l >= d2) ? o : 0u;
    }
    unsigned long long bal = __ballot(cum >= (unsigned int)Kk);
    if (bal != 0ull) {
      int f = __ffsll(bal) - 1;
      unsigned int cumf = (unsigned int)__shfl((int)cum, f, 64);
      unsigned int h1f = (unsigned int)__shfl((int)h1, f, 64);
      int bstar = (cumf - h1f >= (unsigned int)Kk) ? 2 * f : 2 * f + 1;
      // bin top rel = 2*bstar+1; +1 quantum margin (approx keys)
      if (l == 0) hcS[r] = rowminS[r] + 2u * (unsigned int)bstar + 2u;
    } else {
      if (l == 0) { hcS[r] = 0xFFFFFFFFu; atomicOr(&fbS, 1); }
    }
  }
  __syncthreads();

  // ---- level-2 fallback (rare): window 2048 quanta, bins rel>>4 ----
  if (fbS) {
    #pragma unroll
    for (int i = 0; i < 8; i++) {
      int idx = t * 8 + i;
      if (hcS[idx >> 7] == 0xFFFFFFFFu) ((unsigned int*)histS)[idx] = 0u;
    }
    __syncthreads();
    #pragma unroll
    for (int j = 0; j < 16; ++j) {
      #pragma unroll
      for (int h = 0; h < 8; h++) {
        unsigned int pk = kpk[j][h];
        if (hcS[rowE[2 * h]] == 0xFFFFFFFFu) {
          unsigned int r0 = (pk & 0xFFFFu) - rmin[2 * h];
          if (r0 < 2048u) atomicAdd(&histS[rowE[2 * h]][r0 >> 4], 1u);
        }
        if (hcS[rowE[2 * h + 1]] == 0xFFFFFFFFu) {
          unsigned int r1 = (pk >> 16) - rmin[2 * h + 1];
          if (r1 < 2048u) atomicAdd(&histS[rowE[2 * h + 1]][r1 >> 4], 1u);
        }
      }
    }
    __syncthreads();
    #pragma unroll
    for (int i = 0; i < 4; ++i) {
      int r = 4 * w + i;
      if (hcS[r] == 0xFFFFFFFFu) {
        unsigned int h0 = histS[r][2 * l], h1 = histS[r][2 * l + 1];
        unsigned int ls = h0 + h1, cum = ls;
        #pragma unroll
        for (int d2 = 1; d2 < 64; d2 <<= 1) {
          unsigned int o = (unsigned int)__shfl_up((int)cum, d2, 64);
          cum += (l >= d2) ? o : 0u;
        }
        unsigned long long bal = __ballot(cum >= (unsigned int)Kk);
        if (bal != 0ull) {
          int f = __ffsll(bal) - 1;
          unsigned int cumf = (unsigned int)__shfl((int)cum, f, 64);
          unsigned int h1f = (unsigned int)__shfl((int)h1, f, 64);
          int bstar = (cumf - h1f >= (unsigned int)Kk) ? 2 * f : 2 * f + 1;
          if (l == 0) hcS[r] = rowminS[r] + 16u * (unsigned int)bstar + 16u;
        } else {
          if (l == 0) hcS[r] = rowminS[r] + 2047u;  // pathological only
        }
      }
    }
    __syncthreads();
  }

  // ---- pass 4: collect candidates from registers (cap 64/row) ----
  unsigned int hce[16];
  #pragma unroll
  for (int e = 0; e < 16; e++) hce[e] = hcS[rowE[e]];
  #pragma unroll
  for (int j = 0; j < 16; ++j) {
    const int m = m0w + 32 * j + col;
    #pragma unroll
    for (int h = 0; h < 8; h++) {
      unsigned int pk = kpk[j][h];
      if ((pk & 0xFFFFu) <= hce[2 * h]) {
        unsigned int slot = atomicAdd(&cntS[rowE[2 * h]], 1u);
        if (slot < 64u) candS[rowE[2 * h]][slot] = m;
      }
      if ((pk >> 16) <= hce[2 * h + 1]) {
        unsigned int slot = atomicAdd(&cntS[rowE[2 * h + 1]], 1u);
        if (slot < 64u) candS[rowE[2 * h + 1]][slot] = m;
      }
    }
  }
  __syncthreads();

  // ---- pass 5: exact fp32 re-rank + rank-select + output ----
  const float4* xb4 = (const float4*)(x + (size_t)b * Nn * Ff);
  const float* vb = v + (size_t)b * Nn * Ff;
  #pragma unroll 1
  for (int i = 0; i < 4; ++i) {
    const int r = 4 * w + i;
    const int n = n_base + r;
    int C = (int)cntS[r];
    if (C > 64) C = 64;
    // inactive lanes: unique huge keys (lane tiebreak) -> ranks form a
    // permutation; active keys embed mI -> unique.
    unsigned long long key64 = 0xFFFFFFFF00000000ull | (unsigned int)l;
    if (l < C) {
      int mI = candS[r][l];
      const float4* xmf = xb4 + (size_t)mI * 16;
      float ds = 0.f;
      #pragma unroll
      for (int cc = 0; cc < 16; cc++) {
        float4 a = xb4[(size_t)n * 16 + cc];  // wave-uniform
        float4 bb = xmf[cc];
        float dx = a.x - bb.x, dy = a.y - bb.y, dz = a.z - bb.z,
              dw2 = a.w - bb.w;
        ds += dx * dx + dy * dy + dz * dz + dw2 * dw2;
      }
      if (mI == n) ds = FLT_MAX;  // belt-and-braces
      key64 = ((unsigned long long)__float_as_uint(ds) << 32) | (unsigned int)mI;
    }
    // rank via LDS broadcast reads (in-wave ordering; R8-proven)
    keyS[w][l] = key64;
    int rank = 0;
    #pragma unroll
    for (int q = 0; q < 64; q += 4) {
      rank += (keyS[w][q] < key64) + (keyS[w][q + 1] < key64) +
              (keyS[w][q + 2] < key64) + (keyS[w][q + 3] < key64);
    }
    if (rank < Kk)
      candS[r][rank] = (int)(key64 & 0xffffffffu) & (Nn - 1);
    // 20 independent v-gathers + fmax tree
    const size_t oidx = ((size_t)(b * Nn + n)) * 64 + l;
    float uo = u[oidx];
    float vv[Kk];
    #pragma unroll
    for (int g2 = 0; g2 < Kk; g2++) {
      int mI = candS[r][g2];
      vv[g2] = vb[(size_t)mI * 64 + l];
    }
    float vmax = vv[0];
    #pragma unroll
    for (int g2 = 1; g2 < Kk; g2++) vmax = fmaxf(vmax, vv[g2]);
    out[oidx] = uo + vmax;
  }
}

// ---------------- R2 fallback knn (verified) ----------------
constexpr int RTF = 4;
constexpr int MTF = 64;
constexpr int TPADF = 17;
constexpr int CCAPF = 64;

__global__ __launch_bounds__(256) void knn_kernel(
    const float* __restrict__ x, const float* __restrict__ sq,
    const float* __restrict__ u, const float* __restrict__ v,
    float* __restrict__ out) {
  __shared__ __align__(16) float4 tileS[MTF * TPADF];
  __shared__ __align__(16) unsigned short keysS[RTF * Nn];
  __shared__ int candS[RTF * CCAPF];
  __shared__ int ccntS[RTF];
  const int t = threadIdx.x;
  const int l = t & 63, w = t >> 6;
  const int q = l & 15, g = l >> 4;
  const int bn0 = blockIdx.x * RTF;
  const int b = bn0 >> 12;
  const int n0 = bn0 & (Nn - 1);
  const float4* xb4 = (const float4*)(x + (size_t)b * Nn * Ff);
  const float* sqb = sq + b * Nn;
  if (t < RTF) ccntS[t] = 0;
  float4 xnq[RTF][4];
  #pragma unroll
  for (int r = 0; r < RTF; r++)
    #pragma unroll
    for (int c = 0; c < 4; c++) xnq[r][c] = xb4[(n0 + r) * 16 + 4 * g + c];
  const float sn = sqb[n0 + g];
  const int selfm = n0 + g;
  for (int T = 0; T < Nn / MTF; ++T) {
    __syncthreads();
    #pragma unroll
    for (int i = 0; i < 4; i++) {
      int f = t + 256 * i;
      tileS[(f >> 4) * TPADF + (f & 15)] = xb4[T * 1024 + f];
    }
    __syncthreads();
    const int mrow = 16 * w + q;
    const float4* xmp = &tileS[mrow * TPADF + 4 * g];
    float4 xm0 = xmp[0], xm1 = xmp[1], xm2 = xmp[2], xm3 = xmp[3];
    float dot[RTF];
    #pragma unroll
    for (int r = 0; r < RTF; r++) {
      float4 a0 = xnq[r][0], a1 = xnq[r][1], a2 = xnq[r][2], a3 = xnq[r][3];
      dot[r] = a0.x * xm0.x + a0.y * xm0.y + a0.z * xm0.z + a0.w * xm0.w +
               a1.x * xm1.x + a1.y * xm1.y + a1.z * xm1.z + a1.w * xm1.w +
               a2.x * xm2.x + a2.y * xm2.y + a2.z * xm2.z + a2.w * xm2.w +
               a3.x * xm3.x + a3.y * xm3.y + a3.z * xm3.z + a3.w * xm3.w;
    }
    #pragma unroll
    for (int r = 0; r < RTF; r++) {
      dot[r] += __shfl_xor(dot[r], 16, 64);
      dot[r] += __shfl_xor(dot[r], 32, 64);
    }
    float dg = (g == 0) ? dot[0] : (g == 1) ? dot[1] : (g == 2) ? dot[2] : dot[3];
    int m = T * MTF + mrow;
    float d = fmaxf(fmaf(-2.f, dg, sqb[m] + sn), 0.f);
    unsigned int key = __float_as_uint(d) >> 15;
    if (m == selfm) key = 0xFFFFu;
    keysS[g * Nn + m] = (unsigned short)key;
  }
  __syncthreads();
  const unsigned int* kp = (const unsigned int*)&keysS[w * Nn];
  int lo = -1, hi = 65535, cntHi = Nn;
  while (cntHi > 48 && hi - lo > 1) {
    int mid = (lo + hi) >> 1;
    unsigned int midu = (unsigned int)mid;
    int c = 0;
    #pragma unroll
    for (int cc = 0; cc < 8; ++cc) {
      int rc = (cc + l) & 7;
      uint4 k4 = *(const uint4*)(kp + l * 32 + rc * 4);
      c += ((k4.x & 0xffffu) <= midu) + ((k4.x >> 16) <= midu);
      c += ((k4.y & 0xffffu) <= midu) + ((k4.y >> 16) <= midu);
      c += ((k4.z & 0xffffu) <= midu) + ((k4.z >> 16) <= midu);
      c += ((k4.w & 0xffffu) <= midu) + ((k4.w >> 16) <= midu);
    }
    #pragma unroll
    for (int d2 = 1; d2 < 64; d2 <<= 1) c += __shfl_xor(c, d2, 64);
    if (c >= Kk) { hi = mid; cntHi = c; } else { lo = mid; }
  }
  {
    unsigned int hu = (unsigned int)hi;
    #pragma unroll
    for (int cc = 0; cc < 8; ++cc) {
      int rc = (cc + l) & 7;
      uint4 k4 = *(const uint4*)(kp + l * 32 + rc * 4);
      unsigned int ks[4] = {k4.x, k4.y, k4.z, k4.w};
      #pragma unroll
      for (int uu = 0; uu < 4; ++uu) {
        #pragma unroll
        for (int hh = 0; hh < 2; ++hh) {
          unsigned int kvv = hh ? (ks[uu] >> 16) : (ks[uu] & 0xffffu);
          if (kvv <= hu) {
            int slot = atomicAdd(&ccntS[w], 1);
            if (slot < CCAPF) candS[w * CCAPF + slot] = l * 64 + (rc * 4 + uu) * 2 + hh;
          }
        }
      }
    }
  }
  __syncthreads();
  const int n = n0 + w;
  const int C = min(cntHi, CCAPF);
  unsigned long long key64 = ~0ULL;
  if (l < C) {
    int mI = candS[w * CCAPF + l];
    const float4* xmf = xb4 + mI * 16;
    float ds = 0.f;
    #pragma unroll
    for (int c = 0; c < 16; c++) {
      float4 a = xb4[n * 16 + c];
      float4 bb = xmf[c];
      float dx = a.x - bb.x, dy = a.y - bb.y, dz = a.z - bb.z, dw2 = a.w - bb.w;
      ds += dx * dx + dy * dy + dz * dz + dw2 * dw2;
    }
    key64 = ((unsigned long long)__float_as_uint(ds) << 32) | (unsigned int)mI;
  }
  float vmax = -FLT_MAX;
  const float* vb = v + (size_t)b * Nn * Ff;
  #pragma unroll
  for (int it = 0; it < Kk; ++it) {
    unsigned long long kmin = key64;
    #pragma unroll
    for (int d2 = 1; d2 < 64; d2 <<= 1) {
      unsigned long long o =
          (unsigned long long)__shfl_xor((long long)kmin, d2, 64);
      kmin = (o < kmin) ? o : kmin;
    }
    int mI = (int)(kmin & 0xffffffffu) & (Nn - 1);
    vmax = fmaxf(vmax, vb[(size_t)mI * 64 + l]);
    if (key64 == kmin) key64 = ~0ULL;
  }
  const size_t oidx = (size_t)(bn0 + w) * 64 + l;
  out[oidx] = u[oidx] + vmax;
}

extern "C" void kernel_launch(void* const* d_in, const int* in_sizes, int n_in,
                              void* d_out, int out_size, void* d_ws,
                              size_t ws_size, hipStream_t stream) {
  const float* x = (const float*)d_in[0];
  const float* W = (const float*)d_in[1];
  const float* bvec = (const float*)d_in[2];
  float* u = (float*)d_ws;                           // 4 MB
  float* v = u + (size_t)Bb * Nn * Ff;               // 4 MB
  float* sq = v + (size_t)Bb * Nn * Ff;              // 64 KB
  unsigned short* xhi = (unsigned short*)(sq + (size_t)Bb * Nn);  // 2 MB
  unsigned short* xlo = xhi + (size_t)Bb * Nn * Ff;               // 2 MB
  float* out = (float*)d_out;
  const size_t need = (size_t)Bb * Nn * Ff * 4 * 2 + (size_t)Bb * Nn * 4 +
                      (size_t)Bb * Nn * Ff * 2 * 2;  // u,v,sq,xhi,xlo only

  uv_kernel2<<<Bb * Nn / RT1, 256, 0, stream>>>(x, W, bvec, u, v, sq, xhi, xlo);
  if (ws_size >= need) {
    // 4 batches x 128 n-tiles = 512 blocks x 512 threads
    fused_knn_kernel<<<Bb * Nn / 32, 512, 0, stream>>>(x, xhi, xlo, sq, u, v, out);
  } else {
    knn_kernel<<<Bb * Nn / RTF, 256, 0, stream>>>(x, sq, u, v, out);
  }
}

// Round 6
// 258.111 us; speedup vs baseline: 2.4660x; 2.4660x over previous
//
#include <hip/hip_runtime.h>
#include <float.h>

// EdgeConv: B=4, N=4096, Fin=64, Fout=64, K=20
// out[b,n,o] = u[b,n,o] + max_{m in knn20(n)} v[b,m,o]
//   u = x.(W1-W2)^T + bias ; v = x.W2^T
// knn on d = sq[n] + sq[m] - 2 x_n.x_m (>=0), self excluded.
//
// R12 = R11 resubmitted after container-level bench failure (no kernel
// feedback produced). Audit found no OOB/divergent-barrier/unbounded-loop
// vectors; hardened anyway: atomicOr for fbS, explicit histogram-tail
// bound. Structure: register-budget-correct K2+K3 fusion. R10 failed on
// compiler VGPR cap 128 -> full key spill (FETCH 949 MB). Here: half
// m-range per block (32 rows x 2048 m, grid 1024), keys/lane = 128 =
// 64 VGPRs (~200 peak), __launch_bounds__(512,2) allows 256. Pipeline:
// MFMA sweep (keys in regs) -> per-row min -> padded histogram (stride
// 129) -> threshold (+margin) -> collect -> exact fp32 rerank -> 20-entry
// (ds||m) shortlist per (row,half) = 5.2 MB (vs 128 MB keys). merge:
// exact top-20 from 40 entries (union of per-half exact top-20 superset
// of global top-20), v-gather, out. Output identical to R8/R9.

constexpr int Bb = 4, Nn = 4096, Ff = 64, Kk = 20;

typedef __attribute__((ext_vector_type(8))) short bf16x8;
typedef __attribute__((ext_vector_type(16))) float f32x16;

__device__ inline unsigned int bf16rn(float f) {
  unsigned int u = __float_as_uint(f);
  return (u + 0x7fffu + ((u >> 16) & 1u)) >> 16;
}

// ---------------- K1: u, v, sq, xhi, xlo (swizzled) ----------------
constexpr int RT1 = 16;  // rows per block

__global__ __launch_bounds__(256) void uv_kernel2(
    const float* __restrict__ x, const float* __restrict__ W,
    const float* __restrict__ bvec, float* __restrict__ u,
    float* __restrict__ v, float* __restrict__ sq,
    unsigned short* __restrict__ xhi, unsigned short* __restrict__ xlo) {
  __shared__ __align__(16) float4 Ws[64 * 33];   // W row o at granules [33o,33o+32)
  __shared__ __align__(16) float4 xs[RT1 * 16];  // x row r at [16r..)
  const int t = threadIdx.x, l = t & 63, w = t >> 6;
  const int bn0 = blockIdx.x * RT1;
  #pragma unroll
  for (int i = 0; i < 8; i++) {
    int f = t + 256 * i;  // f4 index into W (64 rows x 32 f4)
    Ws[(f >> 5) * 33 + (f & 31)] = ((const float4*)W)[f];
  }
  xs[t] = ((const float4*)x)[bn0 * 16 + t];
  __syncthreads();
  // bf16 hi/lo split -> MFMA-fragment-swizzled layout
  #pragma unroll
  for (int i = 0; i < 4; i++) {
    int idx = t + 256 * i;   // 0..1023 within block's 16 rows
    int nloc = idx >> 6;     // row within block
    int k = idx & 63;        // channel
    float val = ((const float*)xs)[idx];
    unsigned int hb = bf16rn(val);
    float fhi = __uint_as_float(hb << 16);
    unsigned int lb = bf16rn(val - fhi);
    int ng = bn0 + nloc;  // global flat row (batch-local swizzle folds in)
    size_t flat = ((size_t)(ng >> 5) << 11) + ((size_t)(k >> 4) << 9) +
                  ((size_t)((k >> 3) & 1) << 8) + ((size_t)(ng & 31) << 3) +
                  (size_t)(k & 7);
    xhi[flat] = (unsigned short)hb;
    xlo[flat] = (unsigned short)lb;
  }
  // sq for rows 4w..4w+3
  #pragma unroll
  for (int i = 0; i < 4; i++) {
    int r = 4 * w + i;
    float val = ((const float*)&xs[r * 16])[l];
    float s = val * val;
    #pragma unroll
    for (int d = 32; d; d >>= 1) s += __shfl_xor(s, d, 64);
    if (l == 0) sq[bn0 + r] = s;
  }
  const int o = l;
  float ua[4] = {0.f, 0.f, 0.f, 0.f}, va[4] = {0.f, 0.f, 0.f, 0.f};
  #pragma unroll
  for (int c = 0; c < 16; c++) {
    float4 w1 = Ws[o * 33 + c];
    float4 w2 = Ws[o * 33 + 16 + c];
    float4 wd;
    wd.x = w1.x - w2.x; wd.y = w1.y - w2.y;
    wd.z = w1.z - w2.z; wd.w = w1.w - w2.w;
    #pragma unroll
    for (int i = 0; i < 4; i++) {
      float4 xv = xs[(4 * w + i) * 16 + c];
      ua[i] += xv.x * wd.x + xv.y * wd.y + xv.z * wd.z + xv.w * wd.w;
      va[i] += xv.x * w2.x + xv.y * w2.y + xv.z * w2.z + xv.w * w2.w;
    }
  }
  float bo = bvec[o];
  #pragma unroll
  for (int i = 0; i < 4; i++) {
    size_t row = (size_t)(bn0 + 4 * w + i);
    u[row * 64 + o] = ua[i] + bo;
    v[row * 64 + o] = va[i];
  }
}

// ---------------- fused half-kernel: keys in regs, shortlist out --------
// Grid 1024 (= Bb * 128 n-tiles * 2 m-halves). Block 512 thr = 8 waves.
// Wave w: m in [mhalf*2048 + 256w .. +256) over 8 j-tiles of 32.
// C/D: col=lane&31, row=(reg&3)+8*(reg>>2)+4*(lane>>5) [m74/m101].
// Per lane 128 keys packed in 64 VGPRs (static idx only).

__global__ __launch_bounds__(512, 2) void half_knn_kernel(
    const float* __restrict__ x, const unsigned short* __restrict__ xhi,
    const unsigned short* __restrict__ xlo, const float* __restrict__ sq,
    unsigned long long* __restrict__ shortl) {
  __shared__ unsigned int histS[32 * 129];  // stride 129: bank=(row+bin)&31
  __shared__ int candS[32][64];
  __shared__ unsigned int rowminS[32];
  __shared__ unsigned int cntS[32];
  __shared__ unsigned int hcS[32];
  __shared__ unsigned int fbS;
  __shared__ unsigned long long keyS[8][64];

  const int t = threadIdx.x, l = t & 63, w = t >> 6;
  const int blk = blockIdx.x;       // 0..1023
  const int b = blk >> 8;           // batch
  const int r = blk & 255;
  const int n_base = (r >> 1) * 32;
  const int mhalf = r & 1;
  const int m0w = mhalf * 2048 + w * 256;
  const int col = l & 31, hoff = (l >> 5) * 4;

  if (t < 32) { rowminS[t] = 0xFFFFFFFFu; cntS[t] = 0u; }
  if (t == 0) fbS = 0u;
  #pragma unroll
  for (int i = 0; i < 8; i++) histS[t + 512 * i] = 0u;
  if (t < 32) histS[4096 + t] = 0u;  // tail: 32*129-4096 = 32 entries

  const unsigned short* xhb = xhi + (size_t)b * Nn * Ff;
  const unsigned short* xlb = xlo + (size_t)b * Nn * Ff;
  const float* sqb = sq + b * Nn;

  // A fragments (32 rows x 64 ch, hi/lo)
  bf16x8 Ahi[4], Alo[4];
  #pragma unroll
  for (int ks = 0; ks < 4; ks++) {
    size_t off = ((size_t)((n_base >> 5) * 4 + ks) << 9) + ((size_t)l << 3);
    Ahi[ks] = *(const bf16x8*)(xhb + off);
    Alo[ks] = *(const bf16x8*)(xlb + off);
  }
  float sqn_r[16];
  #pragma unroll
  for (int e = 0; e < 16; e++)
    sqn_r[e] = sqb[n_base + (e & 3) + 8 * (e >> 2) + hoff];
  __syncthreads();  // LDS init complete before any atomics

  // ---- pass 1: MFMA sweep; 128 16-bit keys/lane into 64 VGPRs ----
  unsigned int kpk[8][8];  // [j][e>>1]: lo = e even, hi = e odd (STATIC)
  unsigned int kmin[16];
  #pragma unroll
  for (int e = 0; e < 16; e++) kmin[e] = 0xFFFFFFFFu;

  #pragma unroll
  for (int j = 0; j < 8; ++j) {
    const int m0 = m0w + 32 * j;
    const int mblk = m0 >> 5;
    bf16x8 Bhi[4], Blo[4];
    #pragma unroll
    for (int ks = 0; ks < 4; ks++) {
      size_t off = ((size_t)(mblk * 4 + ks) << 9) + ((size_t)l << 3);
      Bhi[ks] = *(const bf16x8*)(xhb + off);
      Blo[ks] = *(const bf16x8*)(xlb + off);
    }
    f32x16 acc = {0.f, 0.f, 0.f, 0.f, 0.f, 0.f, 0.f, 0.f,
                  0.f, 0.f, 0.f, 0.f, 0.f, 0.f, 0.f, 0.f};
    #pragma unroll
    for (int ks = 0; ks < 4; ks++) {
      acc = __builtin_amdgcn_mfma_f32_32x32x16_bf16(Ahi[ks], Bhi[ks], acc, 0, 0, 0);
      acc = __builtin_amdgcn_mfma_f32_32x32x16_bf16(Ahi[ks], Blo[ks], acc, 0, 0, 0);
      acc = __builtin_amdgcn_mfma_f32_32x32x16_bf16(Alo[ks], Bhi[ks], acc, 0, 0, 0);
    }
    const int m = m0 + col;
    const float sm = sqb[m];
    #pragma unroll
    for (int h = 0; h < 8; h++) {
      const int rw0 = ((2 * h) & 3) + 8 * ((2 * h) >> 2) + hoff;
      const int rw1 = ((2 * h + 1) & 3) + 8 * ((2 * h + 1) >> 2) + hoff;
      float d0 = fmaxf(sqn_r[2 * h] + sm - 2.0f * acc[2 * h], 0.f);
      float d1 = fmaxf(sqn_r[2 * h + 1] + sm - 2.0f * acc[2 * h + 1], 0.f);
      unsigned int k0 = __float_as_uint(d0) >> 15;  // fits 16 bits
      unsigned int k1 = __float_as_uint(d1) >> 15;
      if (m == n_base + rw0) k0 = 0xFFFFu;  // self exclusion
      if (m == n_base + rw1) k1 = 0xFFFFu;
      kmin[2 * h] = min(kmin[2 * h], k0);
      kmin[2 * h + 1] = min(kmin[2 * h + 1], k1);
      kpk[j][h] = k0 | (k1 << 16);
    }
  }

  // per-row min: reduce over 32 col-lanes (row lives in one half), atomicMin
  #pragma unroll
  for (int e = 0; e < 16; e++) {
    unsigned int km = kmin[e];
    #pragma unroll
    for (int d2 = 1; d2 < 32; d2 <<= 1)
      km = min(km, (unsigned int)__shfl_xor((int)km, d2, 64));
    if (col == 0)
      atomicMin(&rowminS[(e & 3) + 8 * (e >> 2) + hoff], km);
  }
  __syncthreads();

  // ---- pass 2: histogram bins (key-rowmin)>>1, window 256 quanta ----
  unsigned int rmin[16];
  #pragma unroll
  for (int e = 0; e < 16; e++)
    rmin[e] = rowminS[(e & 3) + 8 * (e >> 2) + hoff];
  #pragma unroll
  for (int j = 0; j < 8; ++j) {
    #pragma unroll
    for (int h = 0; h < 8; h++) {
      const int rw0 = ((2 * h) & 3) + 8 * ((2 * h) >> 2) + hoff;
      const int rw1 = ((2 * h + 1) & 3) + 8 * ((2 * h + 1) >> 2) + hoff;
      unsigned int pk = kpk[j][h];
      unsigned int r0 = (pk & 0xFFFFu) - rmin[2 * h];
      unsigned int r1 = (pk >> 16) - rmin[2 * h + 1];
      if (r0 < 256u) atomicAdd(&histS[rw0 * 129 + (r0 >> 1)], 1u);
      if (r1 < 256u) atomicAdd(&histS[rw1 * 129 + (r1 >> 1)], 1u);
    }
  }
  __syncthreads();

  // ---- pass 3: per-row threshold (wave w owns rows 4w..4w+3) ----
  #pragma unroll
  for (int i = 0; i < 4; ++i) {
    int rr = 4 * w + i;
    unsigned int h0 = histS[rr * 129 + 2 * l], h1 = histS[rr * 129 + 2 * l + 1];
    unsigned int ls = h0 + h1, cum = ls;
    #pragma unroll
    for (int d2 = 1; d2 < 64; d2 <<= 1) {
      unsigned int o = (unsigned int)__shfl_up((int)cum, d2, 64);
      cum += (l >= d2) ? o : 0u;
    }
    unsigned long long bal = __ballot(cum >= (unsigned int)Kk);
    if (bal != 0ull) {
      int f = __ffsll(bal) - 1;
      unsigned int cumf = (unsigned int)__shfl((int)cum, f, 64);
      unsigned int h1f = (unsigned int)__shfl((int)h1, f, 64);
      int bstar = (cumf - h1f >= (unsigned int)Kk) ? 2 * f : 2 * f + 1;
      // bin top rel = 2*bstar+1; +2 margin (approx keys + half-merge)
      if (l == 0) hcS[rr] = rowminS[rr] + 2u * (unsigned int)bstar + 3u;
    } else {
      if (l == 0) { hcS[rr] = 0xFFFFFFFFu; atomicOr(&fbS, 1u); }
    }
  }
  __syncthreads();

  // ---- level-2 fallback (rare): window 2048 quanta, bins rel>>4 ----
  if (fbS) {
    #pragma unroll
    for (int i = 0; i < 8; i++) {
      int idx = t + 512 * i;
      if (hcS[idx / 129] == 0xFFFFFFFFu) histS[idx] = 0u;
    }
    if (t < 32 && hcS[(4096 + t) / 129] == 0xFFFFFFFFu) histS[4096 + t] = 0u;
    __syncthreads();
    #pragma unroll
    for (int j = 0; j < 8; ++j) {
      #pragma unroll
      for (int h = 0; h < 8; h++) {
        const int rw0 = ((2 * h) & 3) + 8 * ((2 * h) >> 2) + hoff;
        const int rw1 = ((2 * h + 1) & 3) + 8 * ((2 * h + 1) >> 2) + hoff;
        unsigned int pk = kpk[j][h];
        if (hcS[rw0] == 0xFFFFFFFFu) {
          unsigned int r0 = (pk & 0xFFFFu) - rmin[2 * h];
          if (r0 < 2048u) atomicAdd(&histS[rw0 * 129 + (r0 >> 4)], 1u);
        }
        if (hcS[rw1] == 0xFFFFFFFFu) {
          unsigned int r1 = (pk >> 16) - rmin[2 * h + 1];
          if (r1 < 2048u) atomicAdd(&histS[rw1 * 129 + (r1 >> 4)], 1u);
        }
      }
    }
    __syncthreads();
    #pragma unroll
    for (int i = 0; i < 4; ++i) {
      int rr = 4 * w + i;
      if (hcS[rr] == 0xFFFFFFFFu) {
        unsigned int h0 = histS[rr * 129 + 2 * l], h1 = histS[rr * 129 + 2 * l + 1];
        unsigned int ls = h0 + h1, cum = ls;
        #pragma unroll
        for (int d2 = 1; d2 < 64; d2 <<= 1) {
          unsigned int o = (unsigned int)__shfl_up((int)cum, d2, 64);
          cum += (l >= d2) ? o : 0u;
        }
        unsigned long long bal = __ballot(cum >= (unsigned int)Kk);
        if (bal != 0ull) {
          int f = __ffsll(bal) - 1;
          unsigned int cumf = (unsigned int)__shfl((int)cum, f, 64);
          unsigned int h1f = (unsigned int)__shfl((int)h1, f, 64);
          int bstar = (cumf - h1f >= (unsigned int)Kk) ? 2 * f : 2 * f + 1;
          if (l == 0) hcS[rr] = rowminS[rr] + 16u * (unsigned int)bstar + 17u;
        } else {
          if (l == 0) hcS[rr] = rowminS[rr] + 2049u;  // pathological only
        }
      }
    }
    __syncthreads();
  }

  // ---- pass 4: collect candidates from registers (cap 64/row) ----
  unsigned int hce[16];
  #pragma unroll
  for (int e = 0; e < 16; e++)
    hce[e] = hcS[(e & 3) + 8 * (e >> 2) + hoff];
  #pragma unroll
  for (int j = 0; j < 8; ++j) {
    const int m = m0w + 32 * j + col;
    #pragma unroll
    for (int h = 0; h < 8; h++) {
      const int rw0 = ((2 * h) & 3) + 8 * ((2 * h) >> 2) + hoff;
      const int rw1 = ((2 * h + 1) & 3) + 8 * ((2 * h + 1) >> 2) + hoff;
      unsigned int pk = kpk[j][h];
      if ((pk & 0xFFFFu) <= hce[2 * h]) {
        unsigned int slot = atomicAdd(&cntS[rw0], 1u);
        if (slot < 64u) candS[rw0][slot] = m;
      }
      if ((pk >> 16) <= hce[2 * h + 1]) {
        unsigned int slot = atomicAdd(&cntS[rw1], 1u);
        if (slot < 64u) candS[rw1][slot] = m;
      }
    }
  }
  __syncthreads();

  // ---- pass 5: exact fp32 re-rank, write 20-entry shortlist ----
  const float4* xb4 = (const float4*)(x + (size_t)b * Nn * Ff);
  #pragma unroll 1
  for (int i = 0; i < 4; ++i) {
    const int rr = 4 * w + i;
    const int n = n_base + rr;
    int C = (int)cntS[rr];
    if (C > 64) C = 64;
    // inactive lanes: unique sentinels (valid m, huge ds; unique across
    // halves via mhalf*2048) -> ranks form a permutation of 0..63 and
    // sentinels self-filter in the merge (ds = 0xFFFFFFFF ranks last).
    unsigned long long key64 =
        0xFFFFFFFF00000000ull | (unsigned int)(mhalf * 2048 + l);
    if (l < C) {
      int mI = candS[rr][l];
      const float4* xmf = xb4 + (size_t)mI * 16;
      float ds = 0.f;
      #pragma unroll
      for (int cc = 0; cc < 16; cc++) {
        float4 a = xb4[(size_t)n * 16 + cc];  // wave-uniform
        float4 bb = xmf[cc];
        float dx = a.x - bb.x, dy = a.y - bb.y, dz = a.z - bb.z,
              dw2 = a.w - bb.w;
        ds += dx * dx + dy * dy + dz * dz + dw2 * dw2;
      }
      if (mI == n) ds = FLT_MAX;  // belt-and-braces
      key64 = ((unsigned long long)__float_as_uint(ds) << 32) | (unsigned int)mI;
    }
    keyS[w][l] = key64;  // same-wave LDS: in-order, no barrier needed
    int rank = 0;
    #pragma unroll
    for (int q = 0; q < 64; q += 4) {
      rank += (keyS[w][q] < key64) + (keyS[w][q + 1] < key64) +
              (keyS[w][q + 2] < key64) + (keyS[w][q + 3] < key64);
    }
    if (rank < Kk)
      shortl[((size_t)(b * Nn + n)) * 40 + mhalf * 20 + rank] = key64;
  }
}

// ---------------- merge: 40 shortlist entries -> exact top-20 -> out ----
__global__ __launch_bounds__(256) void merge_kernel(
    const unsigned long long* __restrict__ shortl,
    const float* __restrict__ u, const float* __restrict__ v,
    float* __restrict__ out) {
  __shared__ int candS[4][32];
  __shared__ unsigned long long keyS[4][64];
  const int t = threadIdx.x, l = t & 63, w = t >> 6;
  const int row = blockIdx.x * 4 + w;  // flat b*N+n
  const int rowu = __builtin_amdgcn_readfirstlane(row);
  const int b = rowu >> 12;
  // lanes >=40: sentinels distinct from half-kernel sentinels (low32 >= 64K)
  unsigned long long key64 =
      (l < 40) ? shortl[(size_t)rowu * 40 + l]
               : (0xFFFFFFFF00000000ull | (unsigned int)(65536 + l));
  keyS[w][l] = key64;
  int rank = 0;
  #pragma unroll
  for (int q = 0; q < 64; q += 4) {
    rank += (keyS[w][q] < key64) + (keyS[w][q + 1] < key64) +
            (keyS[w][q + 2] < key64) + (keyS[w][q + 3] < key64);
  }
  if (rank < Kk)
    candS[w][rank] = (int)(key64 & 0xffffffffu) & (Nn - 1);
  // same-wave in-order LDS: reads below see the writes above
  const float* vb = v + (size_t)b * Nn * Ff;
  const size_t oidx = (size_t)rowu * 64 + l;
  float uo = u[oidx];
  float vv[Kk];
  #pragma unroll
  for (int i = 0; i < Kk; i++) {
    int mI = candS[w][i];
    vv[i] = vb[(size_t)mI * 64 + l];
  }
  float vmax = vv[0];
  #pragma unroll
  for (int i = 1; i < Kk; i++) vmax = fmaxf(vmax, vv[i]);
  out[oidx] = uo + vmax;
}

// ---------------- R2 fallback knn (verified) ----------------
constexpr int RTF = 4;
constexpr int MTF = 64;
constexpr int TPADF = 17;
constexpr int CCAPF = 64;

__global__ __launch_bounds__(256) void knn_kernel(
    const float* __restrict__ x, const float* __restrict__ sq,
    const float* __restrict__ u, const float* __restrict__ v,
    float* __restrict__ out) {
  __shared__ __align__(16) float4 tileS[MTF * TPADF];
  __shared__ __align__(16) unsigned short keysS[RTF * Nn];
  __shared__ int candS[RTF * CCAPF];
  __shared__ int ccntS[RTF];
  const int t = threadIdx.x;
  const int l = t & 63, w = t >> 6;
  const int q = l & 15, g = l >> 4;
  const int bn0 = blockIdx.x * RTF;
  const int b = bn0 >> 12;
  const int n0 = bn0 & (Nn - 1);
  const float4* xb4 = (const float4*)(x + (size_t)b * Nn * Ff);
  const float* sqb = sq + b * Nn;
  if (t < RTF) ccntS[t] = 0;
  float4 xnq[RTF][4];
  #pragma unroll
  for (int r = 0; r < RTF; r++)
    #pragma unroll
    for (int c = 0; c < 4; c++) xnq[r][c] = xb4[(n0 + r) * 16 + 4 * g + c];
  const float sn = sqb[n0 + g];
  const int selfm = n0 + g;
  for (int T = 0; T < Nn / MTF; ++T) {
    __syncthreads();
    #pragma unroll
    for (int i = 0; i < 4; i++) {
      int f = t + 256 * i;
      tileS[(f >> 4) * TPADF + (f & 15)] = xb4[T * 1024 + f];
    }
    __syncthreads();
    const int mrow = 16 * w + q;
    const float4* xmp = &tileS[mrow * TPADF + 4 * g];
    float4 xm0 = xmp[0], xm1 = xmp[1], xm2 = xmp[2], xm3 = xmp[3];
    float dot[RTF];
    #pragma unroll
    for (int r = 0; r < RTF; r++) {
      float4 a0 = xnq[r][0], a1 = xnq[r][1], a2 = xnq[r][2], a3 = xnq[r][3];
      dot[r] = a0.x * xm0.x + a0.y * xm0.y + a0.z * xm0.z + a0.w * xm0.w +
               a1.x * xm1.x + a1.y * xm1.y + a1.z * xm1.z + a1.w * xm1.w +
               a2.x * xm2.x + a2.y * xm2.y + a2.z * xm2.z + a2.w * xm2.w +
               a3.x * xm3.x + a3.y * xm3.y + a3.z * xm3.z + a3.w * xm3.w;
    }
    #pragma unroll
    for (int r = 0; r < RTF; r++) {
      dot[r] += __shfl_xor(dot[r], 16, 64);
      dot[r] += __shfl_xor(dot[r], 32, 64);
    }
    float dg = (g == 0) ? dot[0] : (g == 1) ? dot[1] : (g == 2) ? dot[2] : dot[3];
    int m = T * MTF + mrow;
    float d = fmaxf(fmaf(-2.f, dg, sqb[m] + sn), 0.f);
    unsigned int key = __float_as_uint(d) >> 15;
    if (m == selfm) key = 0xFFFFu;
    keysS[g * Nn + m] = (unsigned short)key;
  }
  __syncthreads();
  const unsigned int* kp = (const unsigned int*)&keysS[w * Nn];
  int lo = -1, hi = 65535, cntHi = Nn;
  while (cntHi > 48 && hi - lo > 1) {
    int mid = (lo + hi) >> 1;
    unsigned int midu = (unsigned int)mid;
    int c = 0;
    #pragma unroll
    for (int cc = 0; cc < 8; ++cc) {
      int rc = (cc + l) & 7;
      uint4 k4 = *(const uint4*)(kp + l * 32 + rc * 4);
      c += ((k4.x & 0xffffu) <= midu) + ((k4.x >> 16) <= midu);
      c += ((k4.y & 0xffffu) <= midu) + ((k4.y >> 16) <= midu);
      c += ((k4.z & 0xffffu) <= midu) + ((k4.z >> 16) <= midu);
      c += ((k4.w & 0xffffu) <= midu) + ((k4.w >> 16) <= midu);
    }
    #pragma unroll
    for (int d2 = 1; d2 < 64; d2 <<= 1) c += __shfl_xor(c, d2, 64);
    if (c >= Kk) { hi = mid; cntHi = c; } else { lo = mid; }
  }
  {
    unsigned int hu = (unsigned int)hi;
    #pragma unroll
    for (int cc = 0; cc < 8; ++cc) {
      int rc = (cc + l) & 7;
      uint4 k4 = *(const uint4*)(kp + l * 32 + rc * 4);
      unsigned int ks[4] = {k4.x, k4.y, k4.z, k4.w};
      #pragma unroll
      for (int uu = 0; uu < 4; ++uu) {
        #pragma unroll
        for (int hh = 0; hh < 2; ++hh) {
          unsigned int kvv = hh ? (ks[uu] >> 16) : (ks[uu] & 0xffffu);
          if (kvv <= hu) {
            int slot = atomicAdd(&ccntS[w], 1);
            if (slot < CCAPF) candS[w * CCAPF + slot] = l * 64 + (rc * 4 + uu) * 2 + hh;
          }
        }
      }
    }
  }
  __syncthreads();
  const int n = n0 + w;
  const int C = min(cntHi, CCAPF);
  unsigned long long key64 = ~0ULL;
  if (l < C) {
    int mI = candS[w * CCAPF + l];
    const float4* xmf = xb4 + mI * 16;
    float ds = 0.f;
    #pragma unroll
    for (int c = 0; c < 16; c++) {
      float4 a = xb4[n * 16 + c];
      float4 bb = xmf[c];
      float dx = a.x - bb.x, dy = a.y - bb.y, dz = a.z - bb.z, dw2 = a.w - bb.w;
      ds += dx * dx + dy * dy + dz * dz + dw2 * dw2;
    }
    key64 = ((unsigned long long)__float_as_uint(ds) << 32) | (unsigned int)mI;
  }
  float vmax = -FLT_MAX;
  const float* vb = v + (size_t)b * Nn * Ff;
  #pragma unroll
  for (int it = 0; it < Kk; ++it) {
    unsigned long long kmin = key64;
    #pragma unroll
    for (int d2 = 1; d2 < 64; d2 <<= 1) {
      unsigned long long o =
          (unsigned long long)__shfl_xor((long long)kmin, d2, 64);
      kmin = (o < kmin) ? o : kmin;
    }
    int mI = (int)(kmin & 0xffffffffu) & (Nn - 1);
    vmax = fmaxf(vmax, vb[(size_t)mI * 64 + l]);
    if (key64 == kmin) key64 = ~0ULL;
  }
  const size_t oidx = (size_t)(bn0 + w) * 64 + l;
  out[oidx] = u[oidx] + vmax;
}

extern "C" void kernel_launch(void* const* d_in, const int* in_sizes, int n_in,
                              void* d_out, int out_size, void* d_ws,
                              size_t ws_size, hipStream_t stream) {
  const float* x = (const float*)d_in[0];
  const float* W = (const float*)d_in[1];
  const float* bvec = (const float*)d_in[2];
  float* u = (float*)d_ws;                           // 4 MB
  float* v = u + (size_t)Bb * Nn * Ff;               // 4 MB
  float* sq = v + (size_t)Bb * Nn * Ff;              // 64 KB
  unsigned short* xhi = (unsigned short*)(sq + (size_t)Bb * Nn);  // 2 MB
  unsigned short* xlo = xhi + (size_t)Bb * Nn * Ff;               // 2 MB
  unsigned long long* shortl = (unsigned long long*)(xlo + (size_t)Bb * Nn * Ff);  // 5.24 MB
  float* out = (float*)d_out;
  const size_t need = (size_t)Bb * Nn * Ff * 4 * 2 + (size_t)Bb * Nn * 4 +
                      (size_t)Bb * Nn * Ff * 2 * 2 +
                      (size_t)Bb * Nn * 40 * 8;  // u,v,sq,xhi,xlo,shortl

  uv_kernel2<<<Bb * Nn / RT1, 256, 0, stream>>>(x, W, bvec, u, v, sq, xhi, xlo);
  if (ws_size >= need) {
    // 4 batches x 128 n-tiles x 2 m-halves = 1024 blocks x 512 threads
    half_knn_kernel<<<Bb * Nn / 16, 512, 0, stream>>>(x, xhi, xlo, sq, shortl);
    merge_kernel<<<Bb * Nn / 4, 256, 0, stream>>>(shortl, u, v, out);
  } else {
    knn_kernel<<<Bb * Nn / RTF, 256, 0, stream>>>(x, sq, u, v, out);
  }
}